// Round 1
// baseline (209.595 us; speedup 1.0000x reference)
//
#include <hip/hip_runtime.h>
#include <math.h>

// Problem constants (from reference)
#define T_STEPS   256
#define N_NEUR    2048
#define N_BATCH   32

// One thread per (batch, neuron). Sequential scan over t in registers.
// Input  layout: in[((b*T + t)*2 + s)*2048 + n]  (b,t,s,n)
// Output layout: out[(b*T + t)*2048 + n]
//
// fp discipline: reference (numpy/XLA-CPU float32) rounds mul and add
// separately — use __fmul_rn/__fadd_rn so hipcc's default fp-contract=fast
// cannot fuse them into FMA and change the trajectory (binary outputs flip
// on ulp-level drift near threshold).
__global__ __launch_bounds__(256) void snn_scan_kernel(
    const float* __restrict__ in,
    float* __restrict__ out,
    float a_mem, float a_s0, float a_s1)
{
    const int tid = blockIdx.x * blockDim.x + threadIdx.x;   // 0..65535
    const int n = tid & (N_NEUR - 1);
    const int b = tid >> 11;

    const float* pin = in + (size_t)b * T_STEPS * 2 * N_NEUR + n;
    float* pout      = out + (size_t)b * T_STEPS * N_NEUR + n;

    float vmem = 0.0f;
    float i0 = 0.0f;
    float i1 = 0.0f;

    // Unroll so the (state-independent) global loads of 8 timesteps issue
    // ahead of the dependent VALU chain — ILP-based latency hiding at
    // 1 wave/SIMD occupancy.
    #pragma unroll 8
    for (int t = 0; t < T_STEPS; ++t) {
        const float x0 = pin[(size_t)t * (2 * N_NEUR)];
        const float x1 = pin[(size_t)t * (2 * N_NEUR) + N_NEUR];

        // isyn = alpha_syn * isyn + x   (mul then add, separate rounding)
        i0 = __fadd_rn(__fmul_rn(a_s0, i0), x0);
        i1 = __fadd_rn(__fmul_rn(a_s1, i1), x1);

        // vmem = alpha_mem * vmem + (isyn0 + isyn1)
        const float ssum = __fadd_rn(i0, i1);
        vmem = __fadd_rn(__fmul_rn(a_mem, vmem), ssum);

        // spike = (vmem - 1 > 0); vmem -= spike * 1
        const float vs = __fsub_rn(vmem, 1.0f);
        const bool fired = (vs > 0.0f);
        const float spike = fired ? 1.0f : 0.0f;
        vmem = fired ? vs : vmem;

        pout[(size_t)t * N_NEUR] = spike;
    }
}

extern "C" void kernel_launch(void* const* d_in, const int* in_sizes, int n_in,
                              void* d_out, int out_size, void* d_ws, size_t ws_size,
                              hipStream_t stream) {
    const float* in = (const float*)d_in[0];
    float* out = (float*)d_out;

    // Correctly-rounded float32 decay constants of exp on the float32-rounded
    // argument: matches jnp.exp(jnp.float32(-1/tau)).
    const float a_s0  = (float)exp((double)(-1.0f / 5.0f));   // tau_syn[0] = 5
    const float a_s1  = (float)exp((double)(-1.0f / 10.0f));  // tau_syn[1] = 10
    const float a_mem = (float)exp((double)(-1.0f / 10.0f));  // tau_mem    = 10

    const int total_threads = N_BATCH * N_NEUR;  // 65536
    dim3 block(256);
    dim3 grid(total_threads / 256);              // 256 blocks -> 1 per CU

    snn_scan_kernel<<<grid, block, 0, stream>>>(in, out, a_mem, a_s0, a_s1);
}